// Round 1
// baseline (728.942 us; speedup 1.0000x reference)
//
#include <hip/hip_runtime.h>
#include <hip/hip_bf16.h>

#define TOK 64
#define DIMC 512

__device__ __forceinline__ unsigned int f2ord(float f) {
  unsigned int u = __float_as_uint(f);
  return (u & 0x80000000u) ? ~u : (u | 0x80000000u);
}

__device__ __forceinline__ float gelu_exact(float x) {
  return 0.5f * x * (1.0f + erff(x * 0.70710678118654752440f));
}

// ---------------------------------------------------------------------------
// Kernel 1: embedding gather + mean-pool -> h [B][1024] (e_t | e_tp1).
// Also initializes rowmin (ws is re-poisoned before every timed launch).
// ---------------------------------------------------------------------------
__global__ __launch_bounds__(256) void k_embed(const int* __restrict__ zt,
                                               const int* __restrict__ ztp,
                                               const float* __restrict__ emb,
                                               float* __restrict__ h,
                                               unsigned long long* __restrict__ rowmin) {
  const int b = blockIdx.x;
  const int tid = threadIdx.x;
  __shared__ int codes[128];
  if (tid < 64) codes[tid] = zt[b * TOK + tid];
  else if (tid < 128) codes[tid] = ztp[b * TOK + (tid - 64)];
  if (tid == 0) rowmin[b] = 0xFFFFFFFFFFFFFFFFull;
  __syncthreads();
  const int half = tid >> 7;   // 0: e_t, 1: e_tp1
  const int c4 = tid & 127;    // float4 chunk within 512 dims
  const float4* emb4 = (const float4*)emb;
  float4 s = make_float4(0.f, 0.f, 0.f, 0.f);
  #pragma unroll 8
  for (int t = 0; t < TOK; t++) {
    const int code = codes[half * TOK + t];
    const float4 v = emb4[code * 128 + c4];
    s.x += v.x; s.y += v.y; s.z += v.z; s.w += v.w;
  }
  const float inv = 1.0f / 64.0f;
  s.x *= inv; s.y *= inv; s.z *= inv; s.w *= inv;
  ((float4*)h)[b * 256 + half * 128 + c4] = s;
}

// ---------------------------------------------------------------------------
// Kernel 2: fused MLP. 8 rows per block, 256 threads.
// h1 = gelu(h @ w1 + b1); e = h1 @ w2 + b2
// ---------------------------------------------------------------------------
__global__ __launch_bounds__(256) void k_mlp(const float* __restrict__ h,
                                             const float* __restrict__ w1,
                                             const float* __restrict__ b1,
                                             const float* __restrict__ w2,
                                             const float* __restrict__ b2,
                                             float* __restrict__ e) {
  __shared__ float hs[8 * 1024];   // 32 KB
  __shared__ float h1s[8 * 512];   // 16 KB
  const int b0 = blockIdx.x * 8;
  const int tid = threadIdx.x;

  const float4* h4 = (const float4*)h;
  #pragma unroll
  for (int i = 0; i < 8; i++)
    ((float4*)hs)[i * 256 + tid] = h4[(b0 + i) * 256 + tid];
  __syncthreads();

  // GEMM1: cols tid and tid+256
  float acc[8][2];
  #pragma unroll
  for (int r = 0; r < 8; r++) { acc[r][0] = 0.f; acc[r][1] = 0.f; }
  for (int k = 0; k < 1024; k += 4) {
    float4 hr[8];
    #pragma unroll
    for (int r = 0; r < 8; r++) hr[r] = *(const float4*)&hs[r * 1024 + k];
    #pragma unroll
    for (int i = 0; i < 4; i++) {
      const float wa = w1[(k + i) * DIMC + tid];
      const float wb = w1[(k + i) * DIMC + tid + 256];
      #pragma unroll
      for (int r = 0; r < 8; r++) {
        const float hv = ((const float*)&hr[r])[i];
        acc[r][0] = fmaf(hv, wa, acc[r][0]);
        acc[r][1] = fmaf(hv, wb, acc[r][1]);
      }
    }
  }
  const float bb0 = b1[tid];
  const float bb1 = b1[tid + 256];
  #pragma unroll
  for (int r = 0; r < 8; r++) {
    h1s[r * 512 + tid] = gelu_exact(acc[r][0] + bb0);
    h1s[r * 512 + tid + 256] = gelu_exact(acc[r][1] + bb1);
  }
  __syncthreads();

  // GEMM2
  float acc2[8][2];
  #pragma unroll
  for (int r = 0; r < 8; r++) { acc2[r][0] = 0.f; acc2[r][1] = 0.f; }
  for (int k = 0; k < 512; k += 4) {
    float4 hr[8];
    #pragma unroll
    for (int r = 0; r < 8; r++) hr[r] = *(const float4*)&h1s[r * 512 + k];
    #pragma unroll
    for (int i = 0; i < 4; i++) {
      const float wa = w2[(k + i) * DIMC + tid];
      const float wb = w2[(k + i) * DIMC + tid + 256];
      #pragma unroll
      for (int r = 0; r < 8; r++) {
        const float hv = ((const float*)&hr[r])[i];
        acc2[r][0] = fmaf(hv, wa, acc2[r][0]);
        acc2[r][1] = fmaf(hv, wb, acc2[r][1]);
      }
    }
  }
  const float c0 = b2[tid];
  const float c1 = b2[tid + 256];
  #pragma unroll
  for (int r = 0; r < 8; r++) {
    e[(b0 + r) * DIMC + tid] = acc2[r][0] + c0;
    e[(b0 + r) * DIMC + tid + 256] = acc2[r][1] + c1;
  }
}

// ---------------------------------------------------------------------------
// Kernel 3: codebook squared norms. One wave per code row.
// ---------------------------------------------------------------------------
__global__ __launch_bounds__(256) void k_cnorm(const float* __restrict__ cb,
                                               float* __restrict__ cnorm) {
  const int row = blockIdx.x * 4 + (threadIdx.x >> 6);
  const int lane = threadIdx.x & 63;
  const float4* cb4 = (const float4*)cb;
  float4 v = cb4[row * 128 + lane];
  float s = v.x * v.x + v.y * v.y + v.z * v.z + v.w * v.w;
  v = cb4[row * 128 + 64 + lane];
  s += v.x * v.x + v.y * v.y + v.z * v.z + v.w * v.w;
  #pragma unroll
  for (int off = 32; off > 0; off >>= 1) s += __shfl_down(s, off);
  if (lane == 0) cnorm[row] = s;
}

// ---------------------------------------------------------------------------
// Kernel 4: VQ score GEMM + per-row argmin.
// 128x128 tile, BK=16, 8x8 micro-tile per thread (16x16 thread grid).
// score = ||c||^2 - 2*e.c  (row-constant ||e||^2 dropped; argmin-invariant)
// ---------------------------------------------------------------------------
#define BM 128
#define BN 128
#define BK 16

__global__ __launch_bounds__(256) void k_vq(const float* __restrict__ e,
                                            const float* __restrict__ cb,
                                            const float* __restrict__ cnorm,
                                            unsigned long long* __restrict__ rowmin) {
  __shared__ alignas(16) unsigned char smem[16384];
  float* As = (float*)smem;                    // [BK][BM] k-major, 8 KB
  float* Bs = (float*)(smem + 8192);           // [BK][BN] k-major, 8 KB
  unsigned long long* red = (unsigned long long*)smem;  // reuse, 128x16 u64

  const int tid = threadIdx.x;
  const int tx = tid & 15;
  const int ty = tid >> 4;
  const int r0 = blockIdx.y * BM;
  const int c0 = blockIdx.x * BN;

  float acc[8][8];
  #pragma unroll
  for (int i = 0; i < 8; i++)
    #pragma unroll
    for (int j = 0; j < 8; j++) acc[i][j] = 0.f;

  for (int k0 = 0; k0 < DIMC; k0 += BK) {
    __syncthreads();  // previous inner-loop readers done
    // Stage A and B tiles (transpose to k-major). 512 float4 each, 2/thread.
    #pragma unroll
    for (int i = 0; i < 2; i++) {
      const int l = tid + i * 256;
      const int r = l >> 2;
      const int k4 = l & 3;
      float4 v = *(const float4*)&e[(r0 + r) * DIMC + k0 + k4 * 4];
      As[(k4 * 4 + 0) * BM + r] = v.x;
      As[(k4 * 4 + 1) * BM + r] = v.y;
      As[(k4 * 4 + 2) * BM + r] = v.z;
      As[(k4 * 4 + 3) * BM + r] = v.w;
      v = *(const float4*)&cb[(c0 + r) * DIMC + k0 + k4 * 4];
      Bs[(k4 * 4 + 0) * BN + r] = v.x;
      Bs[(k4 * 4 + 1) * BN + r] = v.y;
      Bs[(k4 * 4 + 2) * BN + r] = v.z;
      Bs[(k4 * 4 + 3) * BN + r] = v.w;
    }
    __syncthreads();
    #pragma unroll
    for (int kk = 0; kk < BK; kk++) {
      float a[8], b[8];
      *(float4*)&a[0] = *(const float4*)&As[kk * BM + ty * 8];
      *(float4*)&a[4] = *(const float4*)&As[kk * BM + ty * 8 + 4];
      *(float4*)&b[0] = *(const float4*)&Bs[kk * BN + tx * 8];
      *(float4*)&b[4] = *(const float4*)&Bs[kk * BN + tx * 8 + 4];
      #pragma unroll
      for (int i = 0; i < 8; i++)
        #pragma unroll
        for (int j = 0; j < 8; j++)
          acc[i][j] = fmaf(a[i], b[j], acc[i][j]);
    }
  }
  __syncthreads();  // done reading As/Bs; reuse as reduction scratch

  float cn[8];
  #pragma unroll
  for (int j = 0; j < 8; j++) cn[j] = cnorm[c0 + tx * 8 + j];

  #pragma unroll
  for (int i = 0; i < 8; i++) {
    float best = fmaf(-2.f, acc[i][0], cn[0]);
    int bid = c0 + tx * 8;
    #pragma unroll
    for (int j = 1; j < 8; j++) {
      const float s = fmaf(-2.f, acc[i][j], cn[j]);
      if (s < best) { best = s; bid = c0 + tx * 8 + j; }
    }
    red[(ty * 8 + i) * 16 + tx] =
        ((unsigned long long)f2ord(best) << 32) | (unsigned int)bid;
  }
  __syncthreads();
  if (tid < 128) {
    unsigned long long m = red[tid * 16];
    #pragma unroll
    for (int t = 1; t < 16; t++) {
      const unsigned long long v = red[tid * 16 + t];
      if (v < m) m = v;
    }
    atomicMin(&rowmin[r0 + tid], m);
  }
}

// ---------------------------------------------------------------------------
// Kernel 5: finalize — ids as float + gather q rows.
// ---------------------------------------------------------------------------
__global__ __launch_bounds__(64) void k_final(const unsigned long long* __restrict__ rowmin,
                                              const float* __restrict__ cb,
                                              float* __restrict__ out,
                                              int B) {
  const int b = blockIdx.x;
  const int t = threadIdx.x;
  const unsigned long long m = rowmin[b];
  const int id = (int)(unsigned int)(m & 0xFFFFFFFFull);
  if (t == 0) out[b] = (float)id;
  float4* q4 = (float4*)(out + B) + b * 128;
  const float4* cb4 = (const float4*)cb + id * 128;
  q4[t] = cb4[t];
  q4[t + 64] = cb4[t + 64];
}

// ---------------------------------------------------------------------------
extern "C" void kernel_launch(void* const* d_in, const int* in_sizes, int n_in,
                              void* d_out, int out_size, void* d_ws, size_t ws_size,
                              hipStream_t stream) {
  const int* zt = (const int*)d_in[0];
  const int* ztp = (const int*)d_in[1];
  const float* emb = (const float*)d_in[2];
  const float* w1 = (const float*)d_in[3];
  const float* b1 = (const float*)d_in[4];
  const float* w2 = (const float*)d_in[5];
  const float* b2 = (const float*)d_in[6];
  const float* cb = (const float*)d_in[7];
  float* out = (float*)d_out;

  const int B = in_sizes[0] / TOK;        // 2048
  const int A = in_sizes[7] / DIMC;       // 16384

  char* ws = (char*)d_ws;
  float* h = (float*)ws;                                   // B*1024 f32
  float* e = (float*)(ws + (size_t)B * 1024 * 4);          // B*512 f32
  float* cnorm = (float*)(ws + (size_t)B * 1536 * 4);      // A f32
  unsigned long long* rowmin =
      (unsigned long long*)(ws + (size_t)B * 1536 * 4 + (size_t)A * 4);  // B u64

  k_embed<<<B, 256, 0, stream>>>(zt, ztp, emb, h, rowmin);
  k_cnorm<<<A / 4, 256, 0, stream>>>(cb, cnorm);
  k_mlp<<<B / 8, 256, 0, stream>>>(h, w1, b1, w2, b2, e);
  dim3 vq_grid(A / BN, B / BM);
  k_vq<<<vq_grid, 256, 0, stream>>>(e, cb, cnorm, rowmin);
  k_final<<<B, 64, 0, stream>>>(rowmin, cb, out, B);
}

// Round 2
// 378.146 us; speedup vs baseline: 1.9277x; 1.9277x over previous
//
#include <hip/hip_runtime.h>
#include <hip/hip_bf16.h>

#define TOK 64
#define DIMC 512

typedef __attribute__((ext_vector_type(8))) short v8s;   // 8 bf16 = 4 VGPRs
typedef __attribute__((ext_vector_type(4))) float v4f;   // MFMA 16x16 acc

__device__ __forceinline__ unsigned int f2ord(float f) {
  unsigned int u = __float_as_uint(f);
  return (u & 0x80000000u) ? ~u : (u | 0x80000000u);
}

__device__ __forceinline__ float gelu_exact(float x) {
  return 0.5f * x * (1.0f + erff(x * 0.70710678118654752440f));
}

__device__ __forceinline__ unsigned short f2bf(float x) {  // RNE
  unsigned int u = __float_as_uint(x);
  return (unsigned short)((u + 0x7FFFu + ((u >> 16) & 1u)) >> 16);
}
__device__ __forceinline__ float bf2f(unsigned short h) {
  return __uint_as_float((unsigned int)h << 16);
}

__device__ __forceinline__ void gl2lds16(const void* g, void* l) {
  __builtin_amdgcn_global_load_lds((const __attribute__((address_space(1))) void*)g,
                                   (__attribute__((address_space(3))) void*)l,
                                   16, 0, 0);
}

// ---------------------------------------------------------------------------
// Kernel 1: embedding gather + mean-pool -> h [B][1024]; init rowmin.
// ---------------------------------------------------------------------------
__global__ __launch_bounds__(256) void k_embed(const int* __restrict__ zt,
                                               const int* __restrict__ ztp,
                                               const float* __restrict__ emb,
                                               float* __restrict__ h,
                                               unsigned long long* __restrict__ rowmin) {
  const int b = blockIdx.x;
  const int tid = threadIdx.x;
  __shared__ int codes[128];
  if (tid < 64) codes[tid] = zt[b * TOK + tid];
  else if (tid < 128) codes[tid] = ztp[b * TOK + (tid - 64)];
  if (tid == 0) rowmin[b] = 0xFFFFFFFFFFFFFFFFull;
  __syncthreads();
  const int half = tid >> 7;
  const int c4 = tid & 127;
  const float4* emb4 = (const float4*)emb;
  float4 s = make_float4(0.f, 0.f, 0.f, 0.f);
  #pragma unroll 8
  for (int t = 0; t < TOK; t++) {
    const int code = codes[half * TOK + t];
    const float4 v = emb4[code * 128 + c4];
    s.x += v.x; s.y += v.y; s.z += v.z; s.w += v.w;
  }
  const float inv = 1.0f / 64.0f;
  s.x *= inv; s.y *= inv; s.z *= inv; s.w *= inv;
  ((float4*)h)[b * 256 + half * 128 + c4] = s;
}

// ---------------------------------------------------------------------------
// Kernel 2: fused MLP -> e as split bf16 (e_hi + e_lo ~ fp32).
// ---------------------------------------------------------------------------
__global__ __launch_bounds__(256) void k_mlp(const float* __restrict__ h,
                                             const float* __restrict__ w1,
                                             const float* __restrict__ b1,
                                             const float* __restrict__ w2,
                                             const float* __restrict__ b2,
                                             unsigned short* __restrict__ eh,
                                             unsigned short* __restrict__ el) {
  __shared__ float hs[8 * 1024];
  __shared__ float h1s[8 * 512];
  const int b0 = blockIdx.x * 8;
  const int tid = threadIdx.x;

  const float4* h4 = (const float4*)h;
  #pragma unroll
  for (int i = 0; i < 8; i++)
    ((float4*)hs)[i * 256 + tid] = h4[(b0 + i) * 256 + tid];
  __syncthreads();

  float acc[8][2];
  #pragma unroll
  for (int r = 0; r < 8; r++) { acc[r][0] = 0.f; acc[r][1] = 0.f; }
  for (int k = 0; k < 1024; k += 4) {
    float4 hr[8];
    #pragma unroll
    for (int r = 0; r < 8; r++) hr[r] = *(const float4*)&hs[r * 1024 + k];
    #pragma unroll
    for (int i = 0; i < 4; i++) {
      const float wa = w1[(k + i) * DIMC + tid];
      const float wb = w1[(k + i) * DIMC + tid + 256];
      #pragma unroll
      for (int r = 0; r < 8; r++) {
        const float hv = ((const float*)&hr[r])[i];
        acc[r][0] = fmaf(hv, wa, acc[r][0]);
        acc[r][1] = fmaf(hv, wb, acc[r][1]);
      }
    }
  }
  const float bb0 = b1[tid];
  const float bb1 = b1[tid + 256];
  #pragma unroll
  for (int r = 0; r < 8; r++) {
    h1s[r * 512 + tid] = gelu_exact(acc[r][0] + bb0);
    h1s[r * 512 + tid + 256] = gelu_exact(acc[r][1] + bb1);
  }
  __syncthreads();

  float acc2[8][2];
  #pragma unroll
  for (int r = 0; r < 8; r++) { acc2[r][0] = 0.f; acc2[r][1] = 0.f; }
  for (int k = 0; k < 512; k += 4) {
    float4 hr[8];
    #pragma unroll
    for (int r = 0; r < 8; r++) hr[r] = *(const float4*)&h1s[r * 512 + k];
    #pragma unroll
    for (int i = 0; i < 4; i++) {
      const float wa = w2[(k + i) * DIMC + tid];
      const float wb = w2[(k + i) * DIMC + tid + 256];
      #pragma unroll
      for (int r = 0; r < 8; r++) {
        const float hv = ((const float*)&hr[r])[i];
        acc2[r][0] = fmaf(hv, wa, acc2[r][0]);
        acc2[r][1] = fmaf(hv, wb, acc2[r][1]);
      }
    }
  }
  const float c0 = b2[tid];
  const float c1 = b2[tid + 256];
  #pragma unroll
  for (int r = 0; r < 8; r++) {
    const float v0 = acc2[r][0] + c0;
    const float v1 = acc2[r][1] + c1;
    const unsigned short h0 = f2bf(v0);
    const unsigned short h1_ = f2bf(v1);
    eh[(b0 + r) * DIMC + tid] = h0;
    eh[(b0 + r) * DIMC + tid + 256] = h1_;
    el[(b0 + r) * DIMC + tid] = f2bf(v0 - bf2f(h0));
    el[(b0 + r) * DIMC + tid + 256] = f2bf(v1 - bf2f(h1_));
  }
}

// ---------------------------------------------------------------------------
// Kernel 3: codebook prep — split bf16 conversion + squared norms.
// One wave per code row.
// ---------------------------------------------------------------------------
__global__ __launch_bounds__(256) void k_cbprep(const float* __restrict__ cb,
                                                unsigned short* __restrict__ ch,
                                                unsigned short* __restrict__ cl,
                                                float* __restrict__ cnorm) {
  const int row = blockIdx.x * 4 + (threadIdx.x >> 6);
  const int lane = threadIdx.x & 63;
  const float4* cb4 = (const float4*)cb;
  const float4 va = cb4[row * 128 + lane * 2];
  const float4 vb = cb4[row * 128 + lane * 2 + 1];
  float s = va.x * va.x + va.y * va.y + va.z * va.z + va.w * va.w
          + vb.x * vb.x + vb.y * vb.y + vb.z * vb.z + vb.w * vb.w;
  float f[8] = {va.x, va.y, va.z, va.w, vb.x, vb.y, vb.z, vb.w};
  unsigned short hi[8], lo[8];
  #pragma unroll
  for (int i = 0; i < 8; i++) {
    hi[i] = f2bf(f[i]);
    lo[i] = f2bf(f[i] - bf2f(hi[i]));
  }
  ushort4* chp = (ushort4*)&ch[row * DIMC + lane * 8];
  ushort4* clp = (ushort4*)&cl[row * DIMC + lane * 8];
  chp[0] = make_ushort4(hi[0], hi[1], hi[2], hi[3]);
  chp[1] = make_ushort4(hi[4], hi[5], hi[6], hi[7]);
  clp[0] = make_ushort4(lo[0], lo[1], lo[2], lo[3]);
  clp[1] = make_ushort4(lo[4], lo[5], lo[6], lo[7]);
  #pragma unroll
  for (int off = 32; off > 0; off >>= 1) s += __shfl_down(s, off);
  if (lane == 0) cnorm[row] = s;
}

// ---------------------------------------------------------------------------
// Kernel 4: VQ via split-bf16 MFMA GEMM (hh + hl + lh into one accumulator).
// 128x128 tile, BK=32, global_load_lds staging, 16x16x32 bf16 MFMA.
// score = ||c||^2 - 2*e.c  (row-constant ||e||^2 dropped)
// ---------------------------------------------------------------------------
__global__ __launch_bounds__(256, 2) void k_vq(const unsigned short* __restrict__ eh,
                                               const unsigned short* __restrict__ el,
                                               const unsigned short* __restrict__ ch,
                                               const unsigned short* __restrict__ cl,
                                               const float* __restrict__ cnorm,
                                               unsigned long long* __restrict__ rowmin) {
  __shared__ unsigned short Ah[128 * 32];  // 8 KB each, no padding:
  __shared__ unsigned short Al[128 * 32];  // global_load_lds needs contiguous
  __shared__ unsigned short Bh[128 * 32];  // lane order.
  __shared__ unsigned short Bl[128 * 32];

  const int tid = threadIdx.x;
  const int lane = tid & 63;
  const int wid = tid >> 6;
  const int r0 = blockIdx.x * 128;   // e rows (fast-varying: share cb tiles in L2)
  const int c0 = blockIdx.y * 128;   // codebook rows

  v4f acc[4][4];
  #pragma unroll
  for (int i = 0; i < 4; i++)
    #pragma unroll
    for (int j = 0; j < 4; j++) acc[i][j] = (v4f)(0.f);

  // staging: one tile per wave; 8 issues of 16 rows x 32 bf16 (1 KB/wave/issue)
  const int lrow = lane >> 2;          // 0..15
  const int lk = (lane & 3) * 8;       // 0,8,16,24
  const unsigned short* gsrc;
  unsigned short* ldst;
  if (wid == 0)      { gsrc = eh + (size_t)r0 * DIMC; ldst = Ah; }
  else if (wid == 1) { gsrc = el + (size_t)r0 * DIMC; ldst = Al; }
  else if (wid == 2) { gsrc = ch + (size_t)c0 * DIMC; ldst = Bh; }
  else               { gsrc = cl + (size_t)c0 * DIMC; ldst = Bl; }

  const int wm = wid >> 1;   // 0..1: which 64 rows
  const int wn = wid & 1;    // 0..1: which 64 cols
  const int fr = lane & 15;
  const int fq = (lane >> 4) * 8;

  for (int k0 = 0; k0 < DIMC; k0 += 32) {
    __syncthreads();
    #pragma unroll
    for (int j = 0; j < 8; j++)
      gl2lds16(gsrc + (size_t)(j * 16 + lrow) * DIMC + k0 + lk, ldst + j * 512);
    __syncthreads();

    v8s ahf[4], alf[4], bhf[4], blf[4];
    #pragma unroll
    for (int t = 0; t < 4; t++) {
      const int ar = (wm * 64 + t * 16 + fr) * 32 + fq;
      const int br = (wn * 64 + t * 16 + fr) * 32 + fq;
      ahf[t] = *(const v8s*)&Ah[ar];
      alf[t] = *(const v8s*)&Al[ar];
      bhf[t] = *(const v8s*)&Bh[br];
      blf[t] = *(const v8s*)&Bl[br];
    }
    #pragma unroll
    for (int mt = 0; mt < 4; mt++)
      #pragma unroll
      for (int nt = 0; nt < 4; nt++) {
        acc[mt][nt] = __builtin_amdgcn_mfma_f32_16x16x32_bf16(ahf[mt], bhf[nt], acc[mt][nt], 0, 0, 0);
        acc[mt][nt] = __builtin_amdgcn_mfma_f32_16x16x32_bf16(ahf[mt], blf[nt], acc[mt][nt], 0, 0, 0);
        acc[mt][nt] = __builtin_amdgcn_mfma_f32_16x16x32_bf16(alf[mt], bhf[nt], acc[mt][nt], 0, 0, 0);
      }
  }

  // epilogue: C/D layout col=lane&15, row=(lane>>4)*4+reg
  const int col16 = lane & 15;
  const int q = lane >> 4;
  float cn[4];
  #pragma unroll
  for (int nt = 0; nt < 4; nt++) cn[nt] = cnorm[c0 + wn * 64 + nt * 16 + col16];

  #pragma unroll
  for (int mt = 0; mt < 4; mt++) {
    #pragma unroll
    for (int reg = 0; reg < 4; reg++) {
      const int row = r0 + wm * 64 + mt * 16 + q * 4 + reg;
      float best = fmaf(-2.f, acc[mt][0][reg], cn[0]);
      int bid = c0 + wn * 64 + col16;
      #pragma unroll
      for (int nt = 1; nt < 4; nt++) {
        const float s = fmaf(-2.f, acc[mt][nt][reg], cn[nt]);
        const int id = c0 + wn * 64 + nt * 16 + col16;
        if (s < best) { best = s; bid = id; }
      }
      unsigned long long v =
          ((unsigned long long)f2ord(best) << 32) | (unsigned int)bid;
      #pragma unroll
      for (int off = 8; off > 0; off >>= 1) {
        const unsigned long long o = __shfl_down(v, off, 16);
        if (o < v) v = o;
      }
      if (col16 == 0) atomicMin(&rowmin[row], v);
    }
  }
}

// ---------------------------------------------------------------------------
// Kernel 5: finalize — ids as float + gather q rows.
// ---------------------------------------------------------------------------
__global__ __launch_bounds__(64) void k_final(const unsigned long long* __restrict__ rowmin,
                                              const float* __restrict__ cb,
                                              float* __restrict__ out,
                                              int B) {
  const int b = blockIdx.x;
  const int t = threadIdx.x;
  const unsigned long long m = rowmin[b];
  const int id = (int)(unsigned int)(m & 0xFFFFFFFFull);
  if (t == 0) out[b] = (float)id;
  float4* q4 = (float4*)(out + B) + b * 128;
  const float4* cb4 = (const float4*)cb + (size_t)id * 128;
  q4[t] = cb4[t];
  q4[t + 64] = cb4[t + 64];
}

// ---------------------------------------------------------------------------
extern "C" void kernel_launch(void* const* d_in, const int* in_sizes, int n_in,
                              void* d_out, int out_size, void* d_ws, size_t ws_size,
                              hipStream_t stream) {
  const int* zt = (const int*)d_in[0];
  const int* ztp = (const int*)d_in[1];
  const float* emb = (const float*)d_in[2];
  const float* w1 = (const float*)d_in[3];
  const float* b1 = (const float*)d_in[4];
  const float* w2 = (const float*)d_in[5];
  const float* b2 = (const float*)d_in[6];
  const float* cb = (const float*)d_in[7];
  float* out = (float*)d_out;

  const int B = in_sizes[0] / TOK;        // 2048
  const int A = in_sizes[7] / DIMC;       // 16384

  char* p = (char*)d_ws;
  float* h = (float*)p;                 p += (size_t)B * 1024 * 4;
  unsigned short* eh = (unsigned short*)p; p += (size_t)B * DIMC * 2;
  unsigned short* el = (unsigned short*)p; p += (size_t)B * DIMC * 2;
  unsigned short* ch = (unsigned short*)p; p += (size_t)A * DIMC * 2;
  unsigned short* cl = (unsigned short*)p; p += (size_t)A * DIMC * 2;
  float* cnorm = (float*)p;             p += (size_t)A * 4;
  unsigned long long* rowmin = (unsigned long long*)p;

  k_embed<<<B, 256, 0, stream>>>(zt, ztp, emb, h, rowmin);
  k_cbprep<<<A / 4, 256, 0, stream>>>(cb, ch, cl, cnorm);
  k_mlp<<<B / 8, 256, 0, stream>>>(h, w1, b1, w2, b2, eh, el);
  dim3 vq_grid(B / 128, A / 128);
  k_vq<<<vq_grid, 256, 0, stream>>>(eh, el, ch, cl, cnorm, rowmin);
  k_final<<<B, 64, 0, stream>>>(rowmin, cb, out, B);
}

// Round 3
// 251.785 us; speedup vs baseline: 2.8951x; 1.5019x over previous
//
#include <hip/hip_runtime.h>
#include <hip/hip_bf16.h>

#define TOK 64
#define DIMC 512

typedef __attribute__((ext_vector_type(8))) short v8s;   // 8 bf16 = 4 VGPRs
typedef __attribute__((ext_vector_type(4))) float v4f;   // MFMA 16x16 acc

__device__ __forceinline__ unsigned int f2ord(float f) {
  unsigned int u = __float_as_uint(f);
  return (u & 0x80000000u) ? ~u : (u | 0x80000000u);
}

__device__ __forceinline__ float gelu_exact(float x) {
  return 0.5f * x * (1.0f + erff(x * 0.70710678118654752440f));
}

__device__ __forceinline__ unsigned short f2bf(float x) {  // RNE
  unsigned int u = __float_as_uint(x);
  return (unsigned short)((u + 0x7FFFu + ((u >> 16) & 1u)) >> 16);
}
__device__ __forceinline__ float bf2f(unsigned short h) {
  return __uint_as_float((unsigned int)h << 16);
}

__device__ __forceinline__ void gl2lds16(const void* g, void* l) {
  __builtin_amdgcn_global_load_lds((const __attribute__((address_space(1))) void*)g,
                                   (__attribute__((address_space(3))) void*)l,
                                   16, 0, 0);
}

// ---------------------------------------------------------------------------
// Kernel 1: embedding gather + mean-pool -> h [B][1024] as bf16 hi/lo.
// Also initializes rowmin (ws is re-poisoned before every timed launch).
// ---------------------------------------------------------------------------
__global__ __launch_bounds__(256) void k_embed(const int* __restrict__ zt,
                                               const int* __restrict__ ztp,
                                               const float* __restrict__ emb,
                                               unsigned short* __restrict__ hh,
                                               unsigned short* __restrict__ hl,
                                               unsigned long long* __restrict__ rowmin) {
  const int b = blockIdx.x;
  const int tid = threadIdx.x;
  __shared__ int codes[128];
  if (tid < 64) codes[tid] = zt[b * TOK + tid];
  else if (tid < 128) codes[tid] = ztp[b * TOK + (tid - 64)];
  if (tid == 0) rowmin[b] = 0xFFFFFFFFFFFFFFFFull;
  __syncthreads();
  const int half = tid >> 7;
  const int c4 = tid & 127;
  const float4* emb4 = (const float4*)emb;
  float4 s = make_float4(0.f, 0.f, 0.f, 0.f);
  #pragma unroll 8
  for (int t = 0; t < TOK; t++) {
    const int code = codes[half * TOK + t];
    const float4 v = emb4[code * 128 + c4];
    s.x += v.x; s.y += v.y; s.z += v.z; s.w += v.w;
  }
  const float inv = 1.0f / 64.0f;
  float f[4] = {s.x * inv, s.y * inv, s.z * inv, s.w * inv};
  unsigned short hi[4], lo[4];
  #pragma unroll
  for (int i = 0; i < 4; i++) {
    hi[i] = f2bf(f[i]);
    lo[i] = f2bf(f[i] - bf2f(hi[i]));
  }
  const int off = b * 1024 + half * 512 + c4 * 4;
  *(ushort4*)&hh[off] = make_ushort4(hi[0], hi[1], hi[2], hi[3]);
  *(ushort4*)&hl[off] = make_ushort4(lo[0], lo[1], lo[2], lo[3]);
}

// ---------------------------------------------------------------------------
// Kernel 2: weight transpose + split.  w [Kd][N] f32 -> wt_hi/lo [N][Kd] bf16.
// ---------------------------------------------------------------------------
__global__ __launch_bounds__(256) void k_wprep(const float* __restrict__ w,
                                               unsigned short* __restrict__ wth,
                                               unsigned short* __restrict__ wtl,
                                               int Kd, int N) {
  __shared__ float t[32][33];
  const int k0 = blockIdx.x * 32, n0 = blockIdx.y * 32;
  const int c = threadIdx.x & 31, r = threadIdx.x >> 5;  // r: 0..7
  #pragma unroll
  for (int i = 0; i < 4; i++)
    t[r + i * 8][c] = w[(size_t)(k0 + r + i * 8) * N + n0 + c];
  __syncthreads();
  #pragma unroll
  for (int i = 0; i < 4; i++) {
    const float v = t[c][r + i * 8];
    const unsigned short hi = f2bf(v);
    const unsigned short lo = f2bf(v - bf2f(hi));
    wth[(size_t)(n0 + r + i * 8) * Kd + k0 + c] = hi;
    wtl[(size_t)(n0 + r + i * 8) * Kd + k0 + c] = lo;
  }
}

// ---------------------------------------------------------------------------
// Kernel 3: split-bf16 MFMA GEMM: out = A @ Bt^T + bias (optional GELU),
// outputs split bf16. 64x64 tile, BK=32, global_load_lds staging.
// A: [M][Kd] hi/lo, Bt: [N][Kd] hi/lo (k-contiguous), out: [M][512] hi/lo.
// ---------------------------------------------------------------------------
template <bool GELU>
__global__ __launch_bounds__(256) void k_gemm(const unsigned short* __restrict__ Ah_,
                                              const unsigned short* __restrict__ Al_,
                                              const unsigned short* __restrict__ Bh_,
                                              const unsigned short* __restrict__ Bl_,
                                              const float* __restrict__ bias,
                                              unsigned short* __restrict__ oh,
                                              unsigned short* __restrict__ ol,
                                              int Kd, int N) {
  __shared__ unsigned short Ahs[64 * 32];  // 4 KB each, contiguous lane order
  __shared__ unsigned short Als[64 * 32];
  __shared__ unsigned short Bhs[64 * 32];
  __shared__ unsigned short Bls[64 * 32];

  const int tid = threadIdx.x;
  const int lane = tid & 63;
  const int wid = tid >> 6;
  const int m0 = blockIdx.x * 64;
  const int n0 = blockIdx.y * 64;

  v4f acc[2][2];
  #pragma unroll
  for (int i = 0; i < 2; i++)
    #pragma unroll
    for (int j = 0; j < 2; j++) acc[i][j] = (v4f)(0.f);

  const unsigned short* gsrc;
  unsigned short* ldst;
  if (wid == 0)      { gsrc = Ah_ + (size_t)m0 * Kd; ldst = Ahs; }
  else if (wid == 1) { gsrc = Al_ + (size_t)m0 * Kd; ldst = Als; }
  else if (wid == 2) { gsrc = Bh_ + (size_t)n0 * Kd; ldst = Bhs; }
  else               { gsrc = Bl_ + (size_t)n0 * Kd; ldst = Bls; }

  const int srow = lane >> 2;         // 0..15
  const int sk = (lane & 3) * 8;      // shorts
  const int wm = wid >> 1, wn = wid & 1;
  const int fr = lane & 15;
  const int fq = (lane >> 4) * 8;

  for (int k0 = 0; k0 < Kd; k0 += 32) {
    __syncthreads();
    #pragma unroll
    for (int j = 0; j < 4; j++)
      gl2lds16(gsrc + (size_t)(j * 16 + srow) * Kd + k0 + sk, ldst + j * 512);
    __syncthreads();

    v8s ah[2], al[2], bh[2], bl[2];
    #pragma unroll
    for (int t = 0; t < 2; t++) {
      const int ar = (wm * 32 + t * 16 + fr) * 32 + fq;
      const int br = (wn * 32 + t * 16 + fr) * 32 + fq;
      ah[t] = *(const v8s*)&Ahs[ar];
      al[t] = *(const v8s*)&Als[ar];
      bh[t] = *(const v8s*)&Bhs[br];
      bl[t] = *(const v8s*)&Bls[br];
    }
    #pragma unroll
    for (int mt = 0; mt < 2; mt++)
      #pragma unroll
      for (int nt = 0; nt < 2; nt++) {
        acc[mt][nt] = __builtin_amdgcn_mfma_f32_16x16x32_bf16(ah[mt], bh[nt], acc[mt][nt], 0, 0, 0);
        acc[mt][nt] = __builtin_amdgcn_mfma_f32_16x16x32_bf16(ah[mt], bl[nt], acc[mt][nt], 0, 0, 0);
        acc[mt][nt] = __builtin_amdgcn_mfma_f32_16x16x32_bf16(al[mt], bh[nt], acc[mt][nt], 0, 0, 0);
      }
  }

  // epilogue: C/D layout col=lane&15, row=(lane>>4)*4+reg
  const int col16 = lane & 15;
  const int q = lane >> 4;
  int colv[2]; float bv[2];
  #pragma unroll
  for (int nt = 0; nt < 2; nt++) {
    colv[nt] = n0 + wn * 32 + nt * 16 + col16;
    bv[nt] = bias[colv[nt]];
  }
  #pragma unroll
  for (int mt = 0; mt < 2; mt++)
    #pragma unroll
    for (int reg = 0; reg < 4; reg++) {
      const int row = m0 + wm * 32 + mt * 16 + q * 4 + reg;
      #pragma unroll
      for (int nt = 0; nt < 2; nt++) {
        float v = acc[mt][nt][reg] + bv[nt];
        if (GELU) v = gelu_exact(v);
        const unsigned short hi = f2bf(v);
        oh[(size_t)row * N + colv[nt]] = hi;
        ol[(size_t)row * N + colv[nt]] = f2bf(v - bf2f(hi));
      }
    }
}

// ---------------------------------------------------------------------------
// Kernel 4: codebook prep — split bf16 conversion + squared norms.
// ---------------------------------------------------------------------------
__global__ __launch_bounds__(256) void k_cbprep(const float* __restrict__ cb,
                                                unsigned short* __restrict__ ch,
                                                unsigned short* __restrict__ cl,
                                                float* __restrict__ cnorm) {
  const int row = blockIdx.x * 4 + (threadIdx.x >> 6);
  const int lane = threadIdx.x & 63;
  const float4* cb4 = (const float4*)cb;
  const float4 va = cb4[row * 128 + lane * 2];
  const float4 vb = cb4[row * 128 + lane * 2 + 1];
  float s = va.x * va.x + va.y * va.y + va.z * va.z + va.w * va.w
          + vb.x * vb.x + vb.y * vb.y + vb.z * vb.z + vb.w * vb.w;
  float f[8] = {va.x, va.y, va.z, va.w, vb.x, vb.y, vb.z, vb.w};
  unsigned short hi[8], lo[8];
  #pragma unroll
  for (int i = 0; i < 8; i++) {
    hi[i] = f2bf(f[i]);
    lo[i] = f2bf(f[i] - bf2f(hi[i]));
  }
  ushort4* chp = (ushort4*)&ch[row * DIMC + lane * 8];
  ushort4* clp = (ushort4*)&cl[row * DIMC + lane * 8];
  chp[0] = make_ushort4(hi[0], hi[1], hi[2], hi[3]);
  chp[1] = make_ushort4(hi[4], hi[5], hi[6], hi[7]);
  clp[0] = make_ushort4(lo[0], lo[1], lo[2], lo[3]);
  clp[1] = make_ushort4(lo[4], lo[5], lo[6], lo[7]);
  #pragma unroll
  for (int off = 32; off > 0; off >>= 1) s += __shfl_down(s, off);
  if (lane == 0) cnorm[row] = s;
}

// ---------------------------------------------------------------------------
// Kernel 5: VQ via split-bf16 MFMA GEMM (hh + hl + lh into one accumulator).
// 128x128 tile, BK=32, global_load_lds staging, 16x16x32 bf16 MFMA.
// score = ||c||^2 - 2*e.c  (row-constant ||e||^2 dropped)
// ---------------------------------------------------------------------------
__global__ __launch_bounds__(256, 2) void k_vq(const unsigned short* __restrict__ eh,
                                               const unsigned short* __restrict__ el,
                                               const unsigned short* __restrict__ ch,
                                               const unsigned short* __restrict__ cl,
                                               const float* __restrict__ cnorm,
                                               unsigned long long* __restrict__ rowmin) {
  __shared__ unsigned short Ah[128 * 32];
  __shared__ unsigned short Al[128 * 32];
  __shared__ unsigned short Bh[128 * 32];
  __shared__ unsigned short Bl[128 * 32];

  const int tid = threadIdx.x;
  const int lane = tid & 63;
  const int wid = tid >> 6;
  const int r0 = blockIdx.x * 128;
  const int c0 = blockIdx.y * 128;

  v4f acc[4][4];
  #pragma unroll
  for (int i = 0; i < 4; i++)
    #pragma unroll
    for (int j = 0; j < 4; j++) acc[i][j] = (v4f)(0.f);

  const int lrow = lane >> 2;
  const int lk = (lane & 3) * 8;
  const unsigned short* gsrc;
  unsigned short* ldst;
  if (wid == 0)      { gsrc = eh + (size_t)r0 * DIMC; ldst = Ah; }
  else if (wid == 1) { gsrc = el + (size_t)r0 * DIMC; ldst = Al; }
  else if (wid == 2) { gsrc = ch + (size_t)c0 * DIMC; ldst = Bh; }
  else               { gsrc = cl + (size_t)c0 * DIMC; ldst = Bl; }

  const int wm = wid >> 1;
  const int wn = wid & 1;
  const int fr = lane & 15;
  const int fq = (lane >> 4) * 8;

  for (int k0 = 0; k0 < DIMC; k0 += 32) {
    __syncthreads();
    #pragma unroll
    for (int j = 0; j < 8; j++)
      gl2lds16(gsrc + (size_t)(j * 16 + lrow) * DIMC + k0 + lk, ldst + j * 512);
    __syncthreads();

    v8s ahf[4], alf[4], bhf[4], blf[4];
    #pragma unroll
    for (int t = 0; t < 4; t++) {
      const int ar = (wm * 64 + t * 16 + fr) * 32 + fq;
      const int br = (wn * 64 + t * 16 + fr) * 32 + fq;
      ahf[t] = *(const v8s*)&Ah[ar];
      alf[t] = *(const v8s*)&Al[ar];
      bhf[t] = *(const v8s*)&Bh[br];
      blf[t] = *(const v8s*)&Bl[br];
    }
    #pragma unroll
    for (int mt = 0; mt < 4; mt++)
      #pragma unroll
      for (int nt = 0; nt < 4; nt++) {
        acc[mt][nt] = __builtin_amdgcn_mfma_f32_16x16x32_bf16(ahf[mt], bhf[nt], acc[mt][nt], 0, 0, 0);
        acc[mt][nt] = __builtin_amdgcn_mfma_f32_16x16x32_bf16(ahf[mt], blf[nt], acc[mt][nt], 0, 0, 0);
        acc[mt][nt] = __builtin_amdgcn_mfma_f32_16x16x32_bf16(alf[mt], bhf[nt], acc[mt][nt], 0, 0, 0);
      }
  }

  const int col16 = lane & 15;
  const int q = lane >> 4;
  float cn[4];
  #pragma unroll
  for (int nt = 0; nt < 4; nt++) cn[nt] = cnorm[c0 + wn * 64 + nt * 16 + col16];

  #pragma unroll
  for (int mt = 0; mt < 4; mt++) {
    #pragma unroll
    for (int reg = 0; reg < 4; reg++) {
      const int row = r0 + wm * 64 + mt * 16 + q * 4 + reg;
      float best = fmaf(-2.f, acc[mt][0][reg], cn[0]);
      int bid = c0 + wn * 64 + col16;
      #pragma unroll
      for (int nt = 1; nt < 4; nt++) {
        const float s = fmaf(-2.f, acc[mt][nt][reg], cn[nt]);
        const int id = c0 + wn * 64 + nt * 16 + col16;
        if (s < best) { best = s; bid = id; }
      }
      unsigned long long v =
          ((unsigned long long)f2ord(best) << 32) | (unsigned int)bid;
      #pragma unroll
      for (int off = 8; off > 0; off >>= 1) {
        const unsigned long long o = __shfl_down(v, off, 16);
        if (o < v) v = o;
      }
      if (col16 == 0) atomicMin(&rowmin[row], v);
    }
  }
}

// ---------------------------------------------------------------------------
// Kernel 6: finalize — ids as float + gather q rows.
// ---------------------------------------------------------------------------
__global__ __launch_bounds__(64) void k_final(const unsigned long long* __restrict__ rowmin,
                                              const float* __restrict__ cb,
                                              float* __restrict__ out,
                                              int B) {
  const int b = blockIdx.x;
  const int t = threadIdx.x;
  const unsigned long long m = rowmin[b];
  const int id = (int)(unsigned int)(m & 0xFFFFFFFFull);
  if (t == 0) out[b] = (float)id;
  float4* q4 = (float4*)(out + B) + b * 128;
  const float4* cb4 = (const float4*)cb + (size_t)id * 128;
  q4[t] = cb4[t];
  q4[t + 64] = cb4[t + 64];
}

// ---------------------------------------------------------------------------
extern "C" void kernel_launch(void* const* d_in, const int* in_sizes, int n_in,
                              void* d_out, int out_size, void* d_ws, size_t ws_size,
                              hipStream_t stream) {
  const int* zt = (const int*)d_in[0];
  const int* ztp = (const int*)d_in[1];
  const float* emb = (const float*)d_in[2];
  const float* w1 = (const float*)d_in[3];
  const float* b1 = (const float*)d_in[4];
  const float* w2 = (const float*)d_in[5];
  const float* b2 = (const float*)d_in[6];
  const float* cb = (const float*)d_in[7];
  float* out = (float*)d_out;

  const int B = in_sizes[0] / TOK;        // 2048
  const int A = in_sizes[7] / DIMC;       // 16384

  char* p = (char*)d_ws;
  unsigned short* hh = (unsigned short*)p;  p += (size_t)B * 1024 * 2;
  unsigned short* hl = (unsigned short*)p;  p += (size_t)B * 1024 * 2;
  unsigned short* w1th = (unsigned short*)p; p += (size_t)512 * 1024 * 2;
  unsigned short* w1tl = (unsigned short*)p; p += (size_t)512 * 1024 * 2;
  unsigned short* w2th = (unsigned short*)p; p += (size_t)512 * 512 * 2;
  unsigned short* w2tl = (unsigned short*)p; p += (size_t)512 * 512 * 2;
  unsigned short* h1h = (unsigned short*)p; p += (size_t)B * DIMC * 2;
  unsigned short* h1l = (unsigned short*)p; p += (size_t)B * DIMC * 2;
  unsigned short* eh = (unsigned short*)p;  p += (size_t)B * DIMC * 2;
  unsigned short* el = (unsigned short*)p;  p += (size_t)B * DIMC * 2;
  unsigned short* ch = (unsigned short*)p;  p += (size_t)A * DIMC * 2;
  unsigned short* cl = (unsigned short*)p;  p += (size_t)A * DIMC * 2;
  float* cnorm = (float*)p;                 p += (size_t)A * 4;
  unsigned long long* rowmin = (unsigned long long*)p;

  k_embed<<<B, 256, 0, stream>>>(zt, ztp, emb, hh, hl, rowmin);
  k_wprep<<<dim3(1024 / 32, 512 / 32), 256, 0, stream>>>(w1, w1th, w1tl, 1024, 512);
  k_wprep<<<dim3(512 / 32, 512 / 32), 256, 0, stream>>>(w2, w2th, w2tl, 512, 512);
  k_cbprep<<<A / 4, 256, 0, stream>>>(cb, ch, cl, cnorm);
  k_gemm<true><<<dim3(B / 64, 512 / 64), 256, 0, stream>>>(hh, hl, w1th, w1tl, b1, h1h, h1l, 1024, 512);
  k_gemm<false><<<dim3(B / 64, 512 / 64), 256, 0, stream>>>(h1h, h1l, w2th, w2tl, b2, eh, el, 512, 512);
  dim3 vq_grid(B / 128, A / 128);
  k_vq<<<vq_grid, 256, 0, stream>>>(eh, el, ch, cl, cnorm, rowmin);
  k_final<<<B, 64, 0, stream>>>(rowmin, cb, out, B);
}

// Round 4
// 242.850 us; speedup vs baseline: 3.0016x; 1.0368x over previous
//
#include <hip/hip_runtime.h>
#include <hip/hip_bf16.h>

#define TOK 64
#define DIMC 512

typedef __attribute__((ext_vector_type(8))) short v8s;   // 8 bf16 = 4 VGPRs
typedef __attribute__((ext_vector_type(4))) float v4f;   // MFMA 16x16 acc

__device__ __forceinline__ unsigned int f2ord(float f) {
  unsigned int u = __float_as_uint(f);
  return (u & 0x80000000u) ? ~u : (u | 0x80000000u);
}

__device__ __forceinline__ float gelu_exact(float x) {
  return 0.5f * x * (1.0f + erff(x * 0.70710678118654752440f));
}

__device__ __forceinline__ unsigned short f2bf(float x) {  // RNE
  unsigned int u = __float_as_uint(x);
  return (unsigned short)((u + 0x7FFFu + ((u >> 16) & 1u)) >> 16);
}
__device__ __forceinline__ float bf2f(unsigned short h) {
  return __uint_as_float((unsigned int)h << 16);
}

__device__ __forceinline__ void gl2lds16(const void* g, void* l) {
  __builtin_amdgcn_global_load_lds((const __attribute__((address_space(1))) void*)g,
                                   (__attribute__((address_space(3))) void*)l,
                                   16, 0, 0);
}

// ---------------------------------------------------------------------------
// Kernel 1: fused prep. Roles by blockIdx.x:
//   [0,2048)      embed+pool -> hh/hl, init rowmin
//   [2048,2560)   w1 transpose+split
//   [2560,2816)   w2 transpose+split
//   [2816,6912)   codebook split + norms
// ---------------------------------------------------------------------------
__global__ __launch_bounds__(256) void k_prep(
    const int* __restrict__ zt, const int* __restrict__ ztp,
    const float* __restrict__ emb,
    unsigned short* __restrict__ hh, unsigned short* __restrict__ hl,
    unsigned long long* __restrict__ rowmin,
    const float* __restrict__ w1, unsigned short* __restrict__ w1th,
    unsigned short* __restrict__ w1tl,
    const float* __restrict__ w2, unsigned short* __restrict__ w2th,
    unsigned short* __restrict__ w2tl,
    const float* __restrict__ cb, unsigned short* __restrict__ ch,
    unsigned short* __restrict__ cl, float* __restrict__ cnorm) {
  __shared__ int codes[128];
  __shared__ float tbuf[32][33];
  const int bid = blockIdx.x;
  const int tid = threadIdx.x;

  if (bid < 2048) {
    // ---- embed + mean-pool ----
    const int b = bid;
    if (tid < 64) codes[tid] = zt[b * TOK + tid];
    else if (tid < 128) codes[tid] = ztp[b * TOK + (tid - 64)];
    if (tid == 0) rowmin[b] = 0xFFFFFFFFFFFFFFFFull;
    __syncthreads();
    const int half = tid >> 7;
    const int c4 = tid & 127;
    const float4* emb4 = (const float4*)emb;
    float4 s = make_float4(0.f, 0.f, 0.f, 0.f);
    #pragma unroll 8
    for (int t = 0; t < TOK; t++) {
      const int code = codes[half * TOK + t];
      const float4 v = emb4[code * 128 + c4];
      s.x += v.x; s.y += v.y; s.z += v.z; s.w += v.w;
    }
    const float inv = 1.0f / 64.0f;
    float f[4] = {s.x * inv, s.y * inv, s.z * inv, s.w * inv};
    unsigned short hi[4], lo[4];
    #pragma unroll
    for (int i = 0; i < 4; i++) {
      hi[i] = f2bf(f[i]);
      lo[i] = f2bf(f[i] - bf2f(hi[i]));
    }
    const int off = b * 1024 + half * 512 + c4 * 4;
    *(ushort4*)&hh[off] = make_ushort4(hi[0], hi[1], hi[2], hi[3]);
    *(ushort4*)&hl[off] = make_ushort4(lo[0], lo[1], lo[2], lo[3]);
  } else if (bid < 2816) {
    // ---- weight transpose + split ----
    const float* w; unsigned short *wth, *wtl; int Kd, N, k0, n0;
    if (bid < 2560) {
      const int i = bid - 2048;
      w = w1; wth = w1th; wtl = w1tl; Kd = 1024; N = 512;
      k0 = (i & 31) * 32; n0 = (i >> 5) * 32;
    } else {
      const int i = bid - 2560;
      w = w2; wth = w2th; wtl = w2tl; Kd = 512; N = 512;
      k0 = (i & 15) * 32; n0 = (i >> 4) * 32;
    }
    const int c = tid & 31, r = tid >> 5;  // r: 0..7
    #pragma unroll
    for (int i = 0; i < 4; i++)
      tbuf[r + i * 8][c] = w[(size_t)(k0 + r + i * 8) * N + n0 + c];
    __syncthreads();
    #pragma unroll
    for (int i = 0; i < 4; i++) {
      const float v = tbuf[c][r + i * 8];
      const unsigned short hi = f2bf(v);
      const unsigned short lo = f2bf(v - bf2f(hi));
      wth[(size_t)(n0 + r + i * 8) * Kd + k0 + c] = hi;
      wtl[(size_t)(n0 + r + i * 8) * Kd + k0 + c] = lo;
    }
  } else {
    // ---- codebook split + norms (one wave per row) ----
    const int row = (bid - 2816) * 4 + (tid >> 6);
    const int lane = tid & 63;
    const float4* cb4 = (const float4*)cb;
    const float4 va = cb4[row * 128 + lane * 2];
    const float4 vb = cb4[row * 128 + lane * 2 + 1];
    float s = va.x * va.x + va.y * va.y + va.z * va.z + va.w * va.w
            + vb.x * vb.x + vb.y * vb.y + vb.z * vb.z + vb.w * vb.w;
    float f[8] = {va.x, va.y, va.z, va.w, vb.x, vb.y, vb.z, vb.w};
    unsigned short hi[8], lo[8];
    #pragma unroll
    for (int i = 0; i < 8; i++) {
      hi[i] = f2bf(f[i]);
      lo[i] = f2bf(f[i] - bf2f(hi[i]));
    }
    ushort4* chp = (ushort4*)&ch[row * DIMC + lane * 8];
    ushort4* clp = (ushort4*)&cl[row * DIMC + lane * 8];
    chp[0] = make_ushort4(hi[0], hi[1], hi[2], hi[3]);
    chp[1] = make_ushort4(hi[4], hi[5], hi[6], hi[7]);
    clp[0] = make_ushort4(lo[0], lo[1], lo[2], lo[3]);
    clp[1] = make_ushort4(lo[4], lo[5], lo[6], lo[7]);
    #pragma unroll
    for (int off = 32; off > 0; off >>= 1) s += __shfl_down(s, off);
    if (lane == 0) cnorm[row] = s;
  }
}

// ---------------------------------------------------------------------------
// Kernel 2: split-bf16 MFMA GEMM: out = A @ Bt^T + bias (optional GELU),
// outputs split bf16. 64x64 tile, BK=32, global_load_lds staging.
// ---------------------------------------------------------------------------
template <bool GELU>
__global__ __launch_bounds__(256) void k_gemm(const unsigned short* __restrict__ Ah_,
                                              const unsigned short* __restrict__ Al_,
                                              const unsigned short* __restrict__ Bh_,
                                              const unsigned short* __restrict__ Bl_,
                                              const float* __restrict__ bias,
                                              unsigned short* __restrict__ oh,
                                              unsigned short* __restrict__ ol,
                                              int Kd, int N) {
  __shared__ unsigned short Ahs[64 * 32];
  __shared__ unsigned short Als[64 * 32];
  __shared__ unsigned short Bhs[64 * 32];
  __shared__ unsigned short Bls[64 * 32];

  const int tid = threadIdx.x;
  const int lane = tid & 63;
  const int wid = tid >> 6;
  const int m0 = blockIdx.x * 64;
  const int n0 = blockIdx.y * 64;

  v4f acc[2][2];
  #pragma unroll
  for (int i = 0; i < 2; i++)
    #pragma unroll
    for (int j = 0; j < 2; j++) acc[i][j] = (v4f)(0.f);

  const unsigned short* gsrc;
  unsigned short* ldst;
  if (wid == 0)      { gsrc = Ah_ + (size_t)m0 * Kd; ldst = Ahs; }
  else if (wid == 1) { gsrc = Al_ + (size_t)m0 * Kd; ldst = Als; }
  else if (wid == 2) { gsrc = Bh_ + (size_t)n0 * Kd; ldst = Bhs; }
  else               { gsrc = Bl_ + (size_t)n0 * Kd; ldst = Bls; }

  const int srow = lane >> 2;
  const int sk = (lane & 3) * 8;
  const int wm = wid >> 1, wn = wid & 1;
  const int fr = lane & 15;
  const int fq = (lane >> 4) * 8;

  for (int k0 = 0; k0 < Kd; k0 += 32) {
    __syncthreads();
    #pragma unroll
    for (int j = 0; j < 4; j++)
      gl2lds16(gsrc + (size_t)(j * 16 + srow) * Kd + k0 + sk, ldst + j * 512);
    __syncthreads();

    v8s ah[2], al[2], bh[2], bl[2];
    #pragma unroll
    for (int t = 0; t < 2; t++) {
      const int ar = (wm * 32 + t * 16 + fr) * 32 + fq;
      const int br = (wn * 32 + t * 16 + fr) * 32 + fq;
      ah[t] = *(const v8s*)&Ahs[ar];
      al[t] = *(const v8s*)&Als[ar];
      bh[t] = *(const v8s*)&Bhs[br];
      bl[t] = *(const v8s*)&Bls[br];
    }
    #pragma unroll
    for (int mt = 0; mt < 2; mt++)
      #pragma unroll
      for (int nt = 0; nt < 2; nt++) {
        acc[mt][nt] = __builtin_amdgcn_mfma_f32_16x16x32_bf16(ah[mt], bh[nt], acc[mt][nt], 0, 0, 0);
        acc[mt][nt] = __builtin_amdgcn_mfma_f32_16x16x32_bf16(ah[mt], bl[nt], acc[mt][nt], 0, 0, 0);
        acc[mt][nt] = __builtin_amdgcn_mfma_f32_16x16x32_bf16(al[mt], bh[nt], acc[mt][nt], 0, 0, 0);
      }
  }

  const int col16 = lane & 15;
  const int q = lane >> 4;
  int colv[2]; float bv[2];
  #pragma unroll
  for (int nt = 0; nt < 2; nt++) {
    colv[nt] = n0 + wn * 32 + nt * 16 + col16;
    bv[nt] = bias[colv[nt]];
  }
  #pragma unroll
  for (int mt = 0; mt < 2; mt++)
    #pragma unroll
    for (int reg = 0; reg < 4; reg++) {
      const int row = m0 + wm * 32 + mt * 16 + q * 4 + reg;
      #pragma unroll
      for (int nt = 0; nt < 2; nt++) {
        float v = acc[mt][nt][reg] + bv[nt];
        if (GELU) v = gelu_exact(v);
        const unsigned short hi = f2bf(v);
        oh[(size_t)row * N + colv[nt]] = hi;
        ol[(size_t)row * N + colv[nt]] = f2bf(v - bf2f(hi));
      }
    }
}

// ---------------------------------------------------------------------------
// Kernel 3: VQ via split-bf16 MFMA GEMM. 128x128 tile, BK=32, XCD-swizzled
// 1-D grid: the 16 blocks sharing a codebook tile land on one XCD.
// score = ||c||^2 - 2*e.c  (row-constant ||e||^2 dropped)
// ---------------------------------------------------------------------------
__global__ __launch_bounds__(256, 2) void k_vq(const unsigned short* __restrict__ eh,
                                               const unsigned short* __restrict__ el,
                                               const unsigned short* __restrict__ ch,
                                               const unsigned short* __restrict__ cl,
                                               const float* __restrict__ cnorm,
                                               unsigned long long* __restrict__ rowmin) {
  __shared__ unsigned short Ah[128 * 32];
  __shared__ unsigned short Al[128 * 32];
  __shared__ unsigned short Bh[128 * 32];
  __shared__ unsigned short Bl[128 * 32];

  const int tid = threadIdx.x;
  const int lane = tid & 63;
  const int wid = tid >> 6;
  // XCD swizzle: bid%8 selects XCD (dispatch round-robin). Within an XCD
  // (fixed bid&7), consecutive blocks iterate x (e tiles) fastest with a
  // fixed codebook tile y; per-XCD y-sets are disjoint.
  const int bid = blockIdx.x;
  const int j = bid >> 3;
  const int x = j & 15;
  const int y = ((j >> 4) << 3) | (bid & 7);
  const int r0 = x * 128;
  const int c0 = y * 128;

  v4f acc[4][4];
  #pragma unroll
  for (int i = 0; i < 4; i++)
    #pragma unroll
    for (int jj = 0; jj < 4; jj++) acc[i][jj] = (v4f)(0.f);

  const int lrow = lane >> 2;
  const int lk = (lane & 3) * 8;
  const unsigned short* gsrc;
  unsigned short* ldst;
  if (wid == 0)      { gsrc = eh + (size_t)r0 * DIMC; ldst = Ah; }
  else if (wid == 1) { gsrc = el + (size_t)r0 * DIMC; ldst = Al; }
  else if (wid == 2) { gsrc = ch + (size_t)c0 * DIMC; ldst = Bh; }
  else               { gsrc = cl + (size_t)c0 * DIMC; ldst = Bl; }

  const int wm = wid >> 1;
  const int wn = wid & 1;
  const int fr = lane & 15;
  const int fq = (lane >> 4) * 8;

  for (int k0 = 0; k0 < DIMC; k0 += 32) {
    __syncthreads();
    #pragma unroll
    for (int jj = 0; jj < 8; jj++)
      gl2lds16(gsrc + (size_t)(jj * 16 + lrow) * DIMC + k0 + lk, ldst + jj * 512);
    __syncthreads();

    v8s ahf[4], alf[4], bhf[4], blf[4];
    #pragma unroll
    for (int t = 0; t < 4; t++) {
      const int ar = (wm * 64 + t * 16 + fr) * 32 + fq;
      const int br = (wn * 64 + t * 16 + fr) * 32 + fq;
      ahf[t] = *(const v8s*)&Ah[ar];
      alf[t] = *(const v8s*)&Al[ar];
      bhf[t] = *(const v8s*)&Bh[br];
      blf[t] = *(const v8s*)&Bl[br];
    }
    #pragma unroll
    for (int mt = 0; mt < 4; mt++)
      #pragma unroll
      for (int nt = 0; nt < 4; nt++) {
        acc[mt][nt] = __builtin_amdgcn_mfma_f32_16x16x32_bf16(ahf[mt], bhf[nt], acc[mt][nt], 0, 0, 0);
        acc[mt][nt] = __builtin_amdgcn_mfma_f32_16x16x32_bf16(ahf[mt], blf[nt], acc[mt][nt], 0, 0, 0);
        acc[mt][nt] = __builtin_amdgcn_mfma_f32_16x16x32_bf16(alf[mt], bhf[nt], acc[mt][nt], 0, 0, 0);
      }
  }

  const int col16 = lane & 15;
  const int q = lane >> 4;
  float cn[4];
  #pragma unroll
  for (int nt = 0; nt < 4; nt++) cn[nt] = cnorm[c0 + wn * 64 + nt * 16 + col16];

  #pragma unroll
  for (int mt = 0; mt < 4; mt++) {
    #pragma unroll
    for (int reg = 0; reg < 4; reg++) {
      const int row = r0 + wm * 64 + mt * 16 + q * 4 + reg;
      float best = fmaf(-2.f, acc[mt][0][reg], cn[0]);
      int bid2 = c0 + wn * 64 + col16;
      #pragma unroll
      for (int nt = 1; nt < 4; nt++) {
        const float s = fmaf(-2.f, acc[mt][nt][reg], cn[nt]);
        const int id = c0 + wn * 64 + nt * 16 + col16;
        if (s < best) { best = s; bid2 = id; }
      }
      unsigned long long v =
          ((unsigned long long)f2ord(best) << 32) | (unsigned int)bid2;
      #pragma unroll
      for (int off = 8; off > 0; off >>= 1) {
        const unsigned long long o = __shfl_down(v, off, 16);
        if (o < v) v = o;
      }
      if (col16 == 0) atomicMin(&rowmin[row], v);
    }
  }
}

// ---------------------------------------------------------------------------
// Kernel 4: finalize — ids as float + gather q rows.
// ---------------------------------------------------------------------------
__global__ __launch_bounds__(64) void k_final(const unsigned long long* __restrict__ rowmin,
                                              const float* __restrict__ cb,
                                              float* __restrict__ out,
                                              int B) {
  const int b = blockIdx.x;
  const int t = threadIdx.x;
  const unsigned long long m = rowmin[b];
  const int id = (int)(unsigned int)(m & 0xFFFFFFFFull);
  if (t == 0) out[b] = (float)id;
  float4* q4 = (float4*)(out + B) + b * 128;
  const float4* cb4 = (const float4*)cb + (size_t)id * 128;
  q4[t] = cb4[t];
  q4[t + 64] = cb4[t + 64];
}

// ---------------------------------------------------------------------------
extern "C" void kernel_launch(void* const* d_in, const int* in_sizes, int n_in,
                              void* d_out, int out_size, void* d_ws, size_t ws_size,
                              hipStream_t stream) {
  const int* zt = (const int*)d_in[0];
  const int* ztp = (const int*)d_in[1];
  const float* emb = (const float*)d_in[2];
  const float* w1 = (const float*)d_in[3];
  const float* b1 = (const float*)d_in[4];
  const float* w2 = (const float*)d_in[5];
  const float* b2 = (const float*)d_in[6];
  const float* cb = (const float*)d_in[7];
  float* out = (float*)d_out;

  const int B = in_sizes[0] / TOK;        // 2048
  const int A = in_sizes[7] / DIMC;       // 16384

  char* p = (char*)d_ws;
  unsigned short* hh = (unsigned short*)p;  p += (size_t)B * 1024 * 2;
  unsigned short* hl = (unsigned short*)p;  p += (size_t)B * 1024 * 2;
  unsigned short* w1th = (unsigned short*)p; p += (size_t)512 * 1024 * 2;
  unsigned short* w1tl = (unsigned short*)p; p += (size_t)512 * 1024 * 2;
  unsigned short* w2th = (unsigned short*)p; p += (size_t)512 * 512 * 2;
  unsigned short* w2tl = (unsigned short*)p; p += (size_t)512 * 512 * 2;
  unsigned short* h1h = (unsigned short*)p; p += (size_t)B * DIMC * 2;
  unsigned short* h1l = (unsigned short*)p; p += (size_t)B * DIMC * 2;
  unsigned short* eh = (unsigned short*)p;  p += (size_t)B * DIMC * 2;
  unsigned short* el = (unsigned short*)p;  p += (size_t)B * DIMC * 2;
  unsigned short* ch = (unsigned short*)p;  p += (size_t)A * DIMC * 2;
  unsigned short* cl = (unsigned short*)p;  p += (size_t)A * DIMC * 2;
  float* cnorm = (float*)p;                 p += (size_t)A * 4;
  unsigned long long* rowmin = (unsigned long long*)p;

  k_prep<<<2816 + A / 4, 256, 0, stream>>>(zt, ztp, emb, hh, hl, rowmin,
                                           w1, w1th, w1tl, w2, w2th, w2tl,
                                           cb, ch, cl, cnorm);
  k_gemm<true><<<dim3(B / 64, 512 / 64), 256, 0, stream>>>(hh, hl, w1th, w1tl, b1, h1h, h1l, 1024, 512);
  k_gemm<false><<<dim3(B / 64, 512 / 64), 256, 0, stream>>>(h1h, h1l, w2th, w2tl, b2, eh, el, 512, 512);
  k_vq<<<(B / 128) * (A / 128), 256, 0, stream>>>(eh, el, ch, cl, cnorm, rowmin);
  k_final<<<B, 64, 0, stream>>>(rowmin, cb, out, B);
}

// Round 5
// 235.392 us; speedup vs baseline: 3.0967x; 1.0317x over previous
//
#include <hip/hip_runtime.h>
#include <hip/hip_bf16.h>

#define TOK 64
#define DIMC 512

typedef __attribute__((ext_vector_type(8))) short v8s;   // 8 bf16 = 4 VGPRs
typedef __attribute__((ext_vector_type(4))) float v4f;   // MFMA 16x16 acc

__device__ __forceinline__ unsigned int f2ord(float f) {
  unsigned int u = __float_as_uint(f);
  return (u & 0x80000000u) ? ~u : (u | 0x80000000u);
}

__device__ __forceinline__ float gelu_exact(float x) {
  return 0.5f * x * (1.0f + erff(x * 0.70710678118654752440f));
}

__device__ __forceinline__ unsigned short f2bf(float x) {  // RNE
  unsigned int u = __float_as_uint(x);
  return (unsigned short)((u + 0x7FFFu + ((u >> 16) & 1u)) >> 16);
}
__device__ __forceinline__ float bf2f(unsigned short h) {
  return __uint_as_float((unsigned int)h << 16);
}

__device__ __forceinline__ void gl2lds16(const void* g, void* l) {
  __builtin_amdgcn_global_load_lds((const __attribute__((address_space(1))) void*)g,
                                   (__attribute__((address_space(3))) void*)l,
                                   16, 0, 0);
}

// ---------------------------------------------------------------------------
// Kernel 1: fused prep. Roles by blockIdx.x:
//   [0,2048)      embed+pool -> hh/hl, init rowmin
//   [2048,2560)   w1 transpose+split
//   [2560,2816)   w2 transpose+split
//   [2816,6912)   codebook split + norms
// ---------------------------------------------------------------------------
__global__ __launch_bounds__(256) void k_prep(
    const int* __restrict__ zt, const int* __restrict__ ztp,
    const float* __restrict__ emb,
    unsigned short* __restrict__ hh, unsigned short* __restrict__ hl,
    unsigned long long* __restrict__ rowmin,
    const float* __restrict__ w1, unsigned short* __restrict__ w1th,
    unsigned short* __restrict__ w1tl,
    const float* __restrict__ w2, unsigned short* __restrict__ w2th,
    unsigned short* __restrict__ w2tl,
    const float* __restrict__ cb, unsigned short* __restrict__ ch,
    unsigned short* __restrict__ cl, float* __restrict__ cnorm) {
  __shared__ int codes[128];
  __shared__ float tbuf[32][33];
  const int bid = blockIdx.x;
  const int tid = threadIdx.x;

  if (bid < 2048) {
    // ---- embed + mean-pool ----
    const int b = bid;
    if (tid < 64) codes[tid] = zt[b * TOK + tid];
    else if (tid < 128) codes[tid] = ztp[b * TOK + (tid - 64)];
    if (tid == 0) rowmin[b] = 0xFFFFFFFFFFFFFFFFull;
    __syncthreads();
    const int half = tid >> 7;
    const int c4 = tid & 127;
    const float4* emb4 = (const float4*)emb;
    float4 s = make_float4(0.f, 0.f, 0.f, 0.f);
    #pragma unroll 8
    for (int t = 0; t < TOK; t++) {
      const int code = codes[half * TOK + t];
      const float4 v = emb4[code * 128 + c4];
      s.x += v.x; s.y += v.y; s.z += v.z; s.w += v.w;
    }
    const float inv = 1.0f / 64.0f;
    float f[4] = {s.x * inv, s.y * inv, s.z * inv, s.w * inv};
    unsigned short hi[4], lo[4];
    #pragma unroll
    for (int i = 0; i < 4; i++) {
      hi[i] = f2bf(f[i]);
      lo[i] = f2bf(f[i] - bf2f(hi[i]));
    }
    const int off = b * 1024 + half * 512 + c4 * 4;
    *(ushort4*)&hh[off] = make_ushort4(hi[0], hi[1], hi[2], hi[3]);
    *(ushort4*)&hl[off] = make_ushort4(lo[0], lo[1], lo[2], lo[3]);
  } else if (bid < 2816) {
    // ---- weight transpose + split ----
    const float* w; unsigned short *wth, *wtl; int Kd, N, k0, n0;
    if (bid < 2560) {
      const int i = bid - 2048;
      w = w1; wth = w1th; wtl = w1tl; Kd = 1024; N = 512;
      k0 = (i & 31) * 32; n0 = (i >> 5) * 32;
    } else {
      const int i = bid - 2560;
      w = w2; wth = w2th; wtl = w2tl; Kd = 512; N = 512;
      k0 = (i & 15) * 32; n0 = (i >> 4) * 32;
    }
    const int c = tid & 31, r = tid >> 5;  // r: 0..7
    #pragma unroll
    for (int i = 0; i < 4; i++)
      tbuf[r + i * 8][c] = w[(size_t)(k0 + r + i * 8) * N + n0 + c];
    __syncthreads();
    #pragma unroll
    for (int i = 0; i < 4; i++) {
      const float v = tbuf[c][r + i * 8];
      const unsigned short hi = f2bf(v);
      const unsigned short lo = f2bf(v - bf2f(hi));
      wth[(size_t)(n0 + r + i * 8) * Kd + k0 + c] = hi;
      wtl[(size_t)(n0 + r + i * 8) * Kd + k0 + c] = lo;
    }
  } else {
    // ---- codebook split + norms (one wave per row) ----
    const int row = (bid - 2816) * 4 + (tid >> 6);
    const int lane = tid & 63;
    const float4* cb4 = (const float4*)cb;
    const float4 va = cb4[row * 128 + lane * 2];
    const float4 vb = cb4[row * 128 + lane * 2 + 1];
    float s = va.x * va.x + va.y * va.y + va.z * va.z + va.w * va.w
            + vb.x * vb.x + vb.y * vb.y + vb.z * vb.z + vb.w * vb.w;
    float f[8] = {va.x, va.y, va.z, va.w, vb.x, vb.y, vb.z, vb.w};
    unsigned short hi[8], lo[8];
    #pragma unroll
    for (int i = 0; i < 8; i++) {
      hi[i] = f2bf(f[i]);
      lo[i] = f2bf(f[i] - bf2f(hi[i]));
    }
    ushort4* chp = (ushort4*)&ch[row * DIMC + lane * 8];
    ushort4* clp = (ushort4*)&cl[row * DIMC + lane * 8];
    chp[0] = make_ushort4(hi[0], hi[1], hi[2], hi[3]);
    chp[1] = make_ushort4(hi[4], hi[5], hi[6], hi[7]);
    clp[0] = make_ushort4(lo[0], lo[1], lo[2], lo[3]);
    clp[1] = make_ushort4(lo[4], lo[5], lo[6], lo[7]);
    #pragma unroll
    for (int off = 32; off > 0; off >>= 1) s += __shfl_down(s, off);
    if (lane == 0) cnorm[row] = s;
  }
}

// ---------------------------------------------------------------------------
// Kernel 2: split-bf16 MFMA GEMM: out = A @ Bt^T + bias (optional GELU),
// outputs split bf16. 64x64 tile, BK=32, global_load_lds staging.
// ---------------------------------------------------------------------------
template <bool GELU>
__global__ __launch_bounds__(256) void k_gemm(const unsigned short* __restrict__ Ah_,
                                              const unsigned short* __restrict__ Al_,
                                              const unsigned short* __restrict__ Bh_,
                                              const unsigned short* __restrict__ Bl_,
                                              const float* __restrict__ bias,
                                              unsigned short* __restrict__ oh,
                                              unsigned short* __restrict__ ol,
                                              int Kd, int N) {
  __shared__ unsigned short Ahs[64 * 32];
  __shared__ unsigned short Als[64 * 32];
  __shared__ unsigned short Bhs[64 * 32];
  __shared__ unsigned short Bls[64 * 32];

  const int tid = threadIdx.x;
  const int lane = tid & 63;
  const int wid = tid >> 6;
  const int m0 = blockIdx.x * 64;
  const int n0 = blockIdx.y * 64;

  v4f acc[2][2];
  #pragma unroll
  for (int i = 0; i < 2; i++)
    #pragma unroll
    for (int j = 0; j < 2; j++) acc[i][j] = (v4f)(0.f);

  const unsigned short* gsrc;
  unsigned short* ldst;
  if (wid == 0)      { gsrc = Ah_ + (size_t)m0 * Kd; ldst = Ahs; }
  else if (wid == 1) { gsrc = Al_ + (size_t)m0 * Kd; ldst = Als; }
  else if (wid == 2) { gsrc = Bh_ + (size_t)n0 * Kd; ldst = Bhs; }
  else               { gsrc = Bl_ + (size_t)n0 * Kd; ldst = Bls; }

  const int srow = lane >> 2;
  const int sk = (lane & 3) * 8;
  const int wm = wid >> 1, wn = wid & 1;
  const int fr = lane & 15;
  const int fq = (lane >> 4) * 8;

  for (int k0 = 0; k0 < Kd; k0 += 32) {
    __syncthreads();
    #pragma unroll
    for (int j = 0; j < 4; j++)
      gl2lds16(gsrc + (size_t)(j * 16 + srow) * Kd + k0 + sk, ldst + j * 512);
    __syncthreads();

    v8s ah[2], al[2], bh[2], bl[2];
    #pragma unroll
    for (int t = 0; t < 2; t++) {
      const int ar = (wm * 32 + t * 16 + fr) * 32 + fq;
      const int br = (wn * 32 + t * 16 + fr) * 32 + fq;
      ah[t] = *(const v8s*)&Ahs[ar];
      al[t] = *(const v8s*)&Als[ar];
      bh[t] = *(const v8s*)&Bhs[br];
      bl[t] = *(const v8s*)&Bls[br];
    }
    #pragma unroll
    for (int mt = 0; mt < 2; mt++)
      #pragma unroll
      for (int nt = 0; nt < 2; nt++) {
        acc[mt][nt] = __builtin_amdgcn_mfma_f32_16x16x32_bf16(ah[mt], bh[nt], acc[mt][nt], 0, 0, 0);
        acc[mt][nt] = __builtin_amdgcn_mfma_f32_16x16x32_bf16(ah[mt], bl[nt], acc[mt][nt], 0, 0, 0);
        acc[mt][nt] = __builtin_amdgcn_mfma_f32_16x16x32_bf16(al[mt], bh[nt], acc[mt][nt], 0, 0, 0);
      }
  }

  const int col16 = lane & 15;
  const int q = lane >> 4;
  int colv[2]; float bv[2];
  #pragma unroll
  for (int nt = 0; nt < 2; nt++) {
    colv[nt] = n0 + wn * 32 + nt * 16 + col16;
    bv[nt] = bias[colv[nt]];
  }
  #pragma unroll
  for (int mt = 0; mt < 2; mt++)
    #pragma unroll
    for (int reg = 0; reg < 4; reg++) {
      const int row = m0 + wm * 32 + mt * 16 + q * 4 + reg;
      #pragma unroll
      for (int nt = 0; nt < 2; nt++) {
        float v = acc[mt][nt][reg] + bv[nt];
        if (GELU) v = gelu_exact(v);
        const unsigned short hi = f2bf(v);
        oh[(size_t)row * N + colv[nt]] = hi;
        ol[(size_t)row * N + colv[nt]] = f2bf(v - bf2f(hi));
      }
    }
}

// ---------------------------------------------------------------------------
// Kernel 3: VQ via split-bf16 MFMA GEMM. 128x256 block tile, BK=32,
// 64x128 wave tile (4m x 8n of 16x16) -> LDS instr/FLOP cut 1.5x vs 128x128.
// XCD-swizzled 1-D grid. score = ||c||^2 - 2*e.c
// ---------------------------------------------------------------------------
__global__ __launch_bounds__(256, 2) void k_vq(const unsigned short* __restrict__ eh,
                                               const unsigned short* __restrict__ el,
                                               const unsigned short* __restrict__ ch,
                                               const unsigned short* __restrict__ cl,
                                               const float* __restrict__ cnorm,
                                               unsigned long long* __restrict__ rowmin) {
  __shared__ unsigned short Ah[128 * 32];   //  8 KB
  __shared__ unsigned short Al[128 * 32];   //  8 KB
  __shared__ unsigned short Bh[256 * 32];   // 16 KB
  __shared__ unsigned short Bl[256 * 32];   // 16 KB

  const int tid = threadIdx.x;
  const int lane = tid & 63;
  const int wid = tid >> 6;
  // XCD swizzle: bid%8 = XCD; within an XCD consecutive blocks share the
  // codebook tile y, iterating e-tiles x; per-XCD y-sets are disjoint.
  const int bid = blockIdx.x;
  const int j = bid >> 3;
  const int x = j & 15;                      // 16 e-tiles (128 rows)
  const int y = ((j >> 4) << 3) | (bid & 7); // 64 cb-tiles (256 rows)
  const int r0 = x * 128;
  const int c0 = y * 256;

  v4f acc[4][8];
  #pragma unroll
  for (int i = 0; i < 4; i++)
    #pragma unroll
    for (int jj = 0; jj < 8; jj++) acc[i][jj] = (v4f)(0.f);

  const unsigned short* ehB = eh + (size_t)r0 * DIMC;
  const unsigned short* elB = el + (size_t)r0 * DIMC;
  const unsigned short* chB = ch + (size_t)c0 * DIMC;
  const unsigned short* clB = cl + (size_t)c0 * DIMC;

  const int srow = lane >> 2;        // 0..15 rows within an issue
  const int sk = (lane & 3) * 8;     // chunk (shorts)
  const int wm = wid >> 1;           // 2 x 64-row halves
  const int wn = wid & 1;            // 2 x 128-col halves
  const int fr = lane & 15;
  const int fq = (lane >> 4) * 8;

  for (int k0 = 0; k0 < DIMC; k0 += 32) {
    __syncthreads();
    // 48 issues total (Ah 8, Al 8, Bh 16, Bl 16), 12 per wave.
    #pragma unroll
    for (int u = 0; u < 12; u++) {
      const int i = wid * 12 + u;    // wave-uniform
      const unsigned short* gs; unsigned short* ls; int rbase;
      if (i < 8)       { gs = ehB; ls = Ah; rbase = i * 16; }
      else if (i < 16) { gs = elB; ls = Al; rbase = (i - 8) * 16; }
      else if (i < 32) { gs = chB; ls = Bh; rbase = (i - 16) * 16; }
      else             { gs = clB; ls = Bl; rbase = (i - 32) * 16; }
      gl2lds16(gs + (size_t)(rbase + srow) * DIMC + k0 + sk, ls + rbase * 32);
    }
    __syncthreads();

    v8s ahf[4], alf[4];
    #pragma unroll
    for (int mt = 0; mt < 4; mt++) {
      const int ar = (wm * 64 + mt * 16 + fr) * 32 + fq;
      ahf[mt] = *(const v8s*)&Ah[ar];
      alf[mt] = *(const v8s*)&Al[ar];
    }
    #pragma unroll
    for (int nt = 0; nt < 8; nt++) {
      const int br = (wn * 128 + nt * 16 + fr) * 32 + fq;
      const v8s bhf = *(const v8s*)&Bh[br];
      const v8s blf = *(const v8s*)&Bl[br];
      #pragma unroll
      for (int mt = 0; mt < 4; mt++) {
        acc[mt][nt] = __builtin_amdgcn_mfma_f32_16x16x32_bf16(ahf[mt], bhf, acc[mt][nt], 0, 0, 0);
        acc[mt][nt] = __builtin_amdgcn_mfma_f32_16x16x32_bf16(ahf[mt], blf, acc[mt][nt], 0, 0, 0);
        acc[mt][nt] = __builtin_amdgcn_mfma_f32_16x16x32_bf16(alf[mt], bhf, acc[mt][nt], 0, 0, 0);
      }
    }
  }

  // epilogue: C/D layout col=lane&15, row=(lane>>4)*4+reg
  const int col16 = lane & 15;
  const int q = lane >> 4;
  float cn[8];
  #pragma unroll
  for (int nt = 0; nt < 8; nt++) cn[nt] = cnorm[c0 + wn * 128 + nt * 16 + col16];

  #pragma unroll
  for (int mt = 0; mt < 4; mt++) {
    #pragma unroll
    for (int reg = 0; reg < 4; reg++) {
      const int row = r0 + wm * 64 + mt * 16 + q * 4 + reg;
      float best = fmaf(-2.f, acc[mt][0][reg], cn[0]);
      int bid2 = c0 + wn * 128 + col16;
      #pragma unroll
      for (int nt = 1; nt < 8; nt++) {
        const float s = fmaf(-2.f, acc[mt][nt][reg], cn[nt]);
        const int id = c0 + wn * 128 + nt * 16 + col16;
        if (s < best) { best = s; bid2 = id; }
      }
      unsigned long long v =
          ((unsigned long long)f2ord(best) << 32) | (unsigned int)bid2;
      #pragma unroll
      for (int off = 8; off > 0; off >>= 1) {
        const unsigned long long o = __shfl_down(v, off, 16);
        if (o < v) v = o;
      }
      if (col16 == 0) atomicMin(&rowmin[row], v);
    }
  }
}

// ---------------------------------------------------------------------------
// Kernel 4: finalize — ids as float + gather q rows.
// ---------------------------------------------------------------------------
__global__ __launch_bounds__(64) void k_final(const unsigned long long* __restrict__ rowmin,
                                              const float* __restrict__ cb,
                                              float* __restrict__ out,
                                              int B) {
  const int b = blockIdx.x;
  const int t = threadIdx.x;
  const unsigned long long m = rowmin[b];
  const int id = (int)(unsigned int)(m & 0xFFFFFFFFull);
  if (t == 0) out[b] = (float)id;
  float4* q4 = (float4*)(out + B) + b * 128;
  const float4* cb4 = (const float4*)cb + (size_t)id * 128;
  q4[t] = cb4[t];
  q4[t + 64] = cb4[t + 64];
}

// ---------------------------------------------------------------------------
extern "C" void kernel_launch(void* const* d_in, const int* in_sizes, int n_in,
                              void* d_out, int out_size, void* d_ws, size_t ws_size,
                              hipStream_t stream) {
  const int* zt = (const int*)d_in[0];
  const int* ztp = (const int*)d_in[1];
  const float* emb = (const float*)d_in[2];
  const float* w1 = (const float*)d_in[3];
  const float* b1 = (const float*)d_in[4];
  const float* w2 = (const float*)d_in[5];
  const float* b2 = (const float*)d_in[6];
  const float* cb = (const float*)d_in[7];
  float* out = (float*)d_out;

  const int B = in_sizes[0] / TOK;        // 2048
  const int A = in_sizes[7] / DIMC;       // 16384

  char* p = (char*)d_ws;
  unsigned short* hh = (unsigned short*)p;  p += (size_t)B * 1024 * 2;
  unsigned short* hl = (unsigned short*)p;  p += (size_t)B * 1024 * 2;
  unsigned short* w1th = (unsigned short*)p; p += (size_t)512 * 1024 * 2;
  unsigned short* w1tl = (unsigned short*)p; p += (size_t)512 * 1024 * 2;
  unsigned short* w2th = (unsigned short*)p; p += (size_t)512 * 512 * 2;
  unsigned short* w2tl = (unsigned short*)p; p += (size_t)512 * 512 * 2;
  unsigned short* h1h = (unsigned short*)p; p += (size_t)B * DIMC * 2;
  unsigned short* h1l = (unsigned short*)p; p += (size_t)B * DIMC * 2;
  unsigned short* eh = (unsigned short*)p;  p += (size_t)B * DIMC * 2;
  unsigned short* el = (unsigned short*)p;  p += (size_t)B * DIMC * 2;
  unsigned short* ch = (unsigned short*)p;  p += (size_t)A * DIMC * 2;
  unsigned short* cl = (unsigned short*)p;  p += (size_t)A * DIMC * 2;
  float* cnorm = (float*)p;                 p += (size_t)A * 4;
  unsigned long long* rowmin = (unsigned long long*)p;

  k_prep<<<2816 + A / 4, 256, 0, stream>>>(zt, ztp, emb, hh, hl, rowmin,
                                           w1, w1th, w1tl, w2, w2th, w2tl,
                                           cb, ch, cl, cnorm);
  k_gemm<true><<<dim3(B / 64, 512 / 64), 256, 0, stream>>>(hh, hl, w1th, w1tl, b1, h1h, h1l, 1024, 512);
  k_gemm<false><<<dim3(B / 64, 512 / 64), 256, 0, stream>>>(h1h, h1l, w2th, w2tl, b2, eh, el, 512, 512);
  k_vq<<<(B / 128) * (A / 256), 256, 0, stream>>>(eh, el, ch, cl, cnorm, rowmin);
  k_final<<<B, 64, 0, stream>>>(rowmin, cb, out, B);
}